// Round 1
// baseline (531.804 us; speedup 1.0000x reference)
//
#include <hip/hip_runtime.h>
#include <hip/hip_bf16.h>

#define NE   64
#define NH   1024
#define NF   2816
#define TPE  64
#define BK   64
#define PITCH 72   // bf16 elems per LDS row: 144B rows -> 16B aligned, ~2-way banks

typedef __attribute__((ext_vector_type(8))) short bf16x8;
typedef __attribute__((ext_vector_type(4))) float f32x4;

__device__ __forceinline__ ushort f2bf(float f) {
    union { float f; unsigned u; } v; v.f = f;
    unsigned r = v.u + 0x7fffu + ((v.u >> 16) & 1u);
    return (ushort)(r >> 16);
}

// ---------------- Kernel 1: gated = silu(x@w1^T) * (x@w3^T), bf16 out ----------
// grid: (NF/64, NE), block 256 (4 waves). Tile: M=64 tokens x N=64 ff-cols.
__global__ __launch_bounds__(256, 2)
void k1_gate(const float* __restrict__ x,
             const float* __restrict__ w1,
             const float* __restrict__ w3,
             ushort* __restrict__ g) {
    __shared__ ushort lA [64 * PITCH];
    __shared__ ushort lB1[64 * PITCH];
    __shared__ ushort lB3[64 * PITCH];

    const int jt   = blockIdx.x;      // ff tile (0..43)
    const int e    = blockIdx.y;      // expert
    const int tid  = threadIdx.x;
    const int lane = tid & 63;
    const int wid  = tid >> 6;

    const float* xA = x  + (size_t)e * TPE * NH;
    const float* B1 = w1 + ((size_t)e * NF + (size_t)jt * 64) * NH;
    const float* B3 = w3 + ((size_t)e * NF + (size_t)jt * 64) * NH;

    f32x4 acc1[4], acc3[4];
    for (int nf = 0; nf < 4; ++nf) {
        acc1[nf] = f32x4{0.f, 0.f, 0.f, 0.f};
        acc3[nf] = f32x4{0.f, 0.f, 0.f, 0.f};
    }

    for (int kt = 0; kt < NH / BK; ++kt) {   // 16 iters
        __syncthreads();
        // stage 3 x (64 rows x 64 k) fp32 -> bf16 into LDS; 4 float4 per matrix per thread
        #pragma unroll
        for (int r = 0; r < 4; ++r) {
            const int q   = tid + r * 256;          // 0..1023
            const int row = q >> 4;
            const int k4  = (q & 15) * 4;
            const float4 va = *(const float4*)(xA + (size_t)row * NH + kt * BK + k4);
            const float4 v1 = *(const float4*)(B1 + (size_t)row * NH + kt * BK + k4);
            const float4 v3 = *(const float4*)(B3 + (size_t)row * NH + kt * BK + k4);
            ushort4 a, b, c;
            a.x = f2bf(va.x); a.y = f2bf(va.y); a.z = f2bf(va.z); a.w = f2bf(va.w);
            b.x = f2bf(v1.x); b.y = f2bf(v1.y); b.z = f2bf(v1.z); b.w = f2bf(v1.w);
            c.x = f2bf(v3.x); c.y = f2bf(v3.y); c.z = f2bf(v3.z); c.w = f2bf(v3.w);
            *(ushort4*)(&lA [row * PITCH + k4]) = a;
            *(ushort4*)(&lB1[row * PITCH + k4]) = b;
            *(ushort4*)(&lB3[row * PITCH + k4]) = c;
        }
        __syncthreads();

        const int mrow = wid * 16 + (lane & 15);
        #pragma unroll
        for (int ks = 0; ks < 2; ++ks) {
            const int koff = ks * 32 + ((lane >> 4) * 8);
            const bf16x8 af = *(const bf16x8*)(&lA[mrow * PITCH + koff]);
            #pragma unroll
            for (int nf = 0; nf < 4; ++nf) {
                const int brow = (nf * 16 + (lane & 15)) * PITCH + koff;
                const bf16x8 b1 = *(const bf16x8*)(&lB1[brow]);
                acc1[nf] = __builtin_amdgcn_mfma_f32_16x16x32_bf16(af, b1, acc1[nf], 0, 0, 0);
                const bf16x8 b3 = *(const bf16x8*)(&lB3[brow]);
                acc3[nf] = __builtin_amdgcn_mfma_f32_16x16x32_bf16(af, b3, acc3[nf], 0, 0, 0);
            }
        }
    }

    // epilogue: SwiGLU, write bf16 gated. C/D layout: col=lane&15, row=(lane>>4)*4+i
    #pragma unroll
    for (int nf = 0; nf < 4; ++nf) {
        #pragma unroll
        for (int i = 0; i < 4; ++i) {
            const float h1v = acc1[nf][i];
            const float h3v = acc3[nf][i];
            const float s   = (h1v / (1.f + __expf(-h1v))) * h3v;
            const int row = wid * 16 + ((lane >> 4) * 4) + i;
            const int col = jt * 64 + nf * 16 + (lane & 15);
            const size_t t = (size_t)e * TPE + row;
            g[t * NF + col] = f2bf(s);
        }
    }
}

// ---------------- Kernel 2: out = gated @ w2 (per expert), fp32 out ------------
// grid: (NH/64, NE), block 256. Tile: M=64 tokens x N=64 out-cols, K=F.
__global__ __launch_bounds__(256, 2)
void k2_down(const ushort* __restrict__ g,
             const float* __restrict__ w2,
             float* __restrict__ out) {
    __shared__ ushort lA[64 * PITCH];   // [token][k]   natural
    __shared__ ushort lB[64 * PITCH];   // [n(outcol)][k]  transposed on staging

    const int jt   = blockIdx.x;      // out-col tile (0..15)
    const int e    = blockIdx.y;
    const int tid  = threadIdx.x;
    const int lane = tid & 63;
    const int wid  = tid >> 6;

    const ushort* A = g  + (size_t)e * TPE * NF;
    const float*  B = w2 + (size_t)e * NF * NH + (size_t)jt * 64;  // [f][h-sub]
    float* O = out + (size_t)e * TPE * NH + (size_t)jt * 64;

    f32x4 acc[4];
    for (int nf = 0; nf < 4; ++nf) acc[nf] = f32x4{0.f, 0.f, 0.f, 0.f};

    for (int kt = 0; kt < NF / BK; ++kt) {   // 44 iters
        __syncthreads();
        // stage A (already bf16, K-contiguous): 2 x b128 per thread
        #pragma unroll
        for (int r = 0; r < 2; ++r) {
            const int q   = tid + r * 256;     // 0..511
            const int row = q >> 3;
            const int k8  = (q & 7) * 8;
            *(bf16x8*)(&lA[row * PITCH + k8]) =
                *(const bf16x8*)(A + (size_t)row * NF + kt * BK + k8);
        }
        // stage B transposed: thread owns out-col n=tid&63; 4 rounds x 4 strided-k dwords.
        // Each global load: 64 lanes = 64 consecutive h -> 256B coalesced.
        {
            const int n  = tid & 63;
            const int kq = (tid >> 6) * 4;
            #pragma unroll
            for (int r = 0; r < 4; ++r) {
                const int ks = kq + r * 16;
                const size_t base = (size_t)(kt * BK + ks) * NH + n;
                const float f0 = B[base];
                const float f1 = B[base + NH];
                const float f2 = B[base + 2 * (size_t)NH];
                const float f3 = B[base + 3 * (size_t)NH];
                ushort4 b;
                b.x = f2bf(f0); b.y = f2bf(f1); b.z = f2bf(f2); b.w = f2bf(f3);
                *(ushort4*)(&lB[n * PITCH + ks]) = b;
            }
        }
        __syncthreads();

        const int mrow = wid * 16 + (lane & 15);
        #pragma unroll
        for (int ks = 0; ks < 2; ++ks) {
            const int koff = ks * 32 + ((lane >> 4) * 8);
            const bf16x8 af = *(const bf16x8*)(&lA[mrow * PITCH + koff]);
            #pragma unroll
            for (int nf = 0; nf < 4; ++nf) {
                const bf16x8 bfr = *(const bf16x8*)(&lB[(nf * 16 + (lane & 15)) * PITCH + koff]);
                acc[nf] = __builtin_amdgcn_mfma_f32_16x16x32_bf16(af, bfr, acc[nf], 0, 0, 0);
            }
        }
    }

    #pragma unroll
    for (int nf = 0; nf < 4; ++nf) {
        #pragma unroll
        for (int i = 0; i < 4; ++i) {
            const int row = wid * 16 + ((lane >> 4) * 4) + i;
            const int col = nf * 16 + (lane & 15);
            O[(size_t)row * NH + col] = acc[nf][i];
        }
    }
}

extern "C" void kernel_launch(void* const* d_in, const int* in_sizes, int n_in,
                              void* d_out, int out_size, void* d_ws, size_t ws_size,
                              hipStream_t stream) {
    const float* x  = (const float*)d_in[0];
    // d_in[1]: tokens_per_expert (equal split, unused — reference ignores it too)
    const float* w1 = (const float*)d_in[2];
    const float* w3 = (const float*)d_in[3];
    const float* w2 = (const float*)d_in[4];
    float* out = (float*)d_out;
    ushort* gated = (ushort*)d_ws;   // [T][F] bf16, 23.1 MB

    dim3 g1(NF / 64, NE);   // (44, 64)
    k1_gate<<<g1, dim3(256), 0, stream>>>(x, w1, w3, gated);

    dim3 g2(NH / 64, NE);   // (16, 64)
    k2_down<<<g2, dim3(256), 0, stream>>>(gated, w2, out);
}

// Round 2
// 440.566 us; speedup vs baseline: 1.2071x; 1.2071x over previous
//
#include <hip/hip_runtime.h>
#include <hip/hip_bf16.h>

#define NE   64
#define NH   1024
#define NF   2816
#define TPE  64
#define BK   64
#define PITCH 72   // k2 LDS pitch (unchanged, validated)

typedef __attribute__((ext_vector_type(8))) short bf16x8;
typedef __attribute__((ext_vector_type(4))) float f32x4;

__device__ __forceinline__ ushort f2bf(float f) {
    union { float f; unsigned u; } v; v.f = f;
    unsigned r = v.u + 0x7fffu + ((v.u >> 16) & 1u);
    return (ushort)(r >> 16);
}

// convert two f32x4 (lo = k+0..3, hi = k+4..7) into one bf16x8 fragment
__device__ __forceinline__ bf16x8 cvt8(f32x4 lo, f32x4 hi) {
    bf16x8 r;
    #pragma unroll
    for (int j = 0; j < 4; ++j) {
        r[j]     = (short)f2bf(lo[j]);
        r[4 + j] = (short)f2bf(hi[j]);
    }
    return r;
}

#define GLOAD16(gsrc, ldst)                                                          \
    __builtin_amdgcn_global_load_lds(                                                \
        (const __attribute__((address_space(1))) void*)(gsrc),                       \
        (__attribute__((address_space(3))) void*)(ldst), 16, 0, 0)

// ---------------- Kernel 1: gated = silu(x@w1^T) * (x@w3^T), bf16 out ----------
// grid: (NF/64, NE), block 256 (4 waves). Tile: M=64 tokens x N=64 ff-cols.
// f32 tiles staged to LDS via global_load_lds (linear dest); bank-conflict
// swizzle applied by pre-swizzling the GLOBAL source: 16B slot col' = col ^ (row&15).
// Read side probes the same involution. f32->bf16 happens at fragment load.
__global__ __launch_bounds__(256, 3)
void k1_gate(const float* __restrict__ x,
             const float* __restrict__ w1,
             const float* __restrict__ w3,
             ushort* __restrict__ g) {
    __shared__ float lA [64 * 64];   // 16 KB each, 48 KB total -> 3 blocks/CU
    __shared__ float lB1[64 * 64];
    __shared__ float lB3[64 * 64];

    const int jt   = blockIdx.x;
    const int e    = blockIdx.y;
    const int tid  = threadIdx.x;
    const int lane = tid & 63;
    const int wid  = tid >> 6;
    const int m15  = lane & 15;
    const int hi   = lane >> 4;

    const float* xA = x  + (size_t)e * TPE * NH;
    const float* B1 = w1 + ((size_t)e * NF + (size_t)jt * 64) * NH;
    const float* B3 = w3 + ((size_t)e * NF + (size_t)jt * 64) * NH;

    f32x4 acc1[4], acc3[4];
    #pragma unroll
    for (int nf = 0; nf < 4; ++nf) {
        acc1[nf] = f32x4{0.f, 0.f, 0.f, 0.f};
        acc3[nf] = f32x4{0.f, 0.f, 0.f, 0.f};
    }

    const int mrow = wid * 16 + m15;

    for (int kt = 0; kt < NH / BK; ++kt) {   // 16 iters
        __syncthreads();   // all waves done reading previous tile
        // stage 3 x (64 rows x 64 f32) via global_load_lds, 4 insts/thread/matrix.
        // slot s (16B units): row = s>>4, LDS col = s&15 holds global col (s&15)^(row&15)
        #pragma unroll
        for (int r = 0; r < 4; ++r) {
            const int s    = r * 256 + tid;
            const int row  = s >> 4;
            const int c16  = (s & 15) ^ (row & 15);
            const size_t goff = (size_t)row * NH + (size_t)kt * BK + c16 * 4;
            const int lbase = (s & ~63) * 4;       // wave-uniform base (floats)
            GLOAD16(xA + goff, lA  + lbase);
            GLOAD16(B1 + goff, lB1 + lbase);
            GLOAD16(B3 + goff, lB3 + lbase);
        }
        __syncthreads();   // compiler drains vmcnt(0) before barrier -> tiles landed

        #pragma unroll
        for (int ks = 0; ks < 2; ++ks) {
            const int c0 = ks * 8 + hi * 2;        // 16B-slot col, even
            const int sa0 = (c0    ) ^ m15;        // mrow&15 == m15
            const int sa1 = (c0 + 1) ^ m15;
            const f32x4 a0 = *(const f32x4*)&lA[mrow * 64 + sa0 * 4];
            const f32x4 a1 = *(const f32x4*)&lA[mrow * 64 + sa1 * 4];
            const bf16x8 af = cvt8(a0, a1);
            #pragma unroll
            for (int nf = 0; nf < 4; ++nf) {
                const int brow = nf * 16 + m15;    // brow&15 == m15
                const f32x4 p0 = *(const f32x4*)&lB1[brow * 64 + sa0 * 4];
                const f32x4 p1 = *(const f32x4*)&lB1[brow * 64 + sa1 * 4];
                acc1[nf] = __builtin_amdgcn_mfma_f32_16x16x32_bf16(af, cvt8(p0, p1), acc1[nf], 0, 0, 0);
                const f32x4 q0 = *(const f32x4*)&lB3[brow * 64 + sa0 * 4];
                const f32x4 q1 = *(const f32x4*)&lB3[brow * 64 + sa1 * 4];
                acc3[nf] = __builtin_amdgcn_mfma_f32_16x16x32_bf16(af, cvt8(q0, q1), acc3[nf], 0, 0, 0);
            }
        }
    }

    // epilogue: SwiGLU, write bf16 gated. C/D layout: col=lane&15, row=(lane>>4)*4+i
    #pragma unroll
    for (int nf = 0; nf < 4; ++nf) {
        #pragma unroll
        for (int i = 0; i < 4; ++i) {
            const float h1v = acc1[nf][i];
            const float h3v = acc3[nf][i];
            const float s   = (h1v / (1.f + __expf(-h1v))) * h3v;
            const int row = wid * 16 + (hi * 4) + i;
            const int col = jt * 64 + nf * 16 + m15;
            const size_t t = (size_t)e * TPE + row;
            g[t * NF + col] = f2bf(s);
        }
    }
}

// ---------------- Kernel 2: out = gated @ w2 (per expert), fp32 out ------------
// (unchanged from R1 — measured ~104 us, at/below its 117 us HBM floor)
__global__ __launch_bounds__(256, 2)
void k2_down(const ushort* __restrict__ g,
             const float* __restrict__ w2,
             float* __restrict__ out) {
    __shared__ ushort lA[64 * PITCH];
    __shared__ ushort lB[64 * PITCH];

    const int jt   = blockIdx.x;
    const int e    = blockIdx.y;
    const int tid  = threadIdx.x;
    const int lane = tid & 63;
    const int wid  = tid >> 6;

    const ushort* A = g  + (size_t)e * TPE * NF;
    const float*  B = w2 + (size_t)e * NF * NH + (size_t)jt * 64;
    float* O = out + (size_t)e * TPE * NH + (size_t)jt * 64;

    f32x4 acc[4];
    for (int nf = 0; nf < 4; ++nf) acc[nf] = f32x4{0.f, 0.f, 0.f, 0.f};

    for (int kt = 0; kt < NF / BK; ++kt) {   // 44 iters
        __syncthreads();
        #pragma unroll
        for (int r = 0; r < 2; ++r) {
            const int q   = tid + r * 256;
            const int row = q >> 3;
            const int k8  = (q & 7) * 8;
            *(bf16x8*)(&lA[row * PITCH + k8]) =
                *(const bf16x8*)(A + (size_t)row * NF + kt * BK + k8);
        }
        {
            const int n  = tid & 63;
            const int kq = (tid >> 6) * 4;
            #pragma unroll
            for (int r = 0; r < 4; ++r) {
                const int ks = kq + r * 16;
                const size_t base = (size_t)(kt * BK + ks) * NH + n;
                const float f0 = B[base];
                const float f1 = B[base + NH];
                const float f2 = B[base + 2 * (size_t)NH];
                const float f3 = B[base + 3 * (size_t)NH];
                ushort4 b;
                b.x = f2bf(f0); b.y = f2bf(f1); b.z = f2bf(f2); b.w = f2bf(f3);
                *(ushort4*)(&lB[n * PITCH + ks]) = b;
            }
        }
        __syncthreads();

        const int mrow = wid * 16 + (lane & 15);
        #pragma unroll
        for (int ks = 0; ks < 2; ++ks) {
            const int koff = ks * 32 + ((lane >> 4) * 8);
            const bf16x8 af = *(const bf16x8*)(&lA[mrow * PITCH + koff]);
            #pragma unroll
            for (int nf = 0; nf < 4; ++nf) {
                const bf16x8 bfr = *(const bf16x8*)(&lB[(nf * 16 + (lane & 15)) * PITCH + koff]);
                acc[nf] = __builtin_amdgcn_mfma_f32_16x16x32_bf16(af, bfr, acc[nf], 0, 0, 0);
            }
        }
    }

    #pragma unroll
    for (int nf = 0; nf < 4; ++nf) {
        #pragma unroll
        for (int i = 0; i < 4; ++i) {
            const int row = wid * 16 + ((lane >> 4) * 4) + i;
            const int col = nf * 16 + (lane & 15);
            O[(size_t)row * NH + col] = acc[nf][i];
        }
    }
}

extern "C" void kernel_launch(void* const* d_in, const int* in_sizes, int n_in,
                              void* d_out, int out_size, void* d_ws, size_t ws_size,
                              hipStream_t stream) {
    const float* x  = (const float*)d_in[0];
    const float* w1 = (const float*)d_in[2];
    const float* w3 = (const float*)d_in[3];
    const float* w2 = (const float*)d_in[4];
    float* out = (float*)d_out;
    ushort* gated = (ushort*)d_ws;   // [T][F] bf16, 23.1 MB

    dim3 g1(NF / 64, NE);   // (44, 64)
    k1_gate<<<g1, dim3(256), 0, stream>>>(x, w1, w3, gated);

    dim3 g2(NH / 64, NE);   // (16, 64)
    k2_down<<<g2, dim3(256), 0, stream>>>(gated, w2, out);
}